// Round 14
// baseline (275.357 us; speedup 1.0000x reference)
//
#include <hip/hip_runtime.h>
#include <stdint.h>

typedef unsigned short u16;
typedef __attribute__((ext_vector_type(8))) short short8;
typedef __attribute__((ext_vector_type(4))) short short4v;
typedef __attribute__((ext_vector_type(4))) float floatx4;

#define AS_GLOBAL __attribute__((address_space(1)))
#define AS_LDS    __attribute__((address_space(3)))

// exp2 argument scale folded into Qp: 1/sqrt(1024) * log2(e)
#define QSCALE 0.045084220f

__device__ __forceinline__ float bf2f(u16 u) {
  union { unsigned int i; float f; } x; x.i = ((unsigned int)u) << 16; return x.f;
}
__device__ __forceinline__ u16 f2bf(float f) {          // RNE
  union { float f; unsigned int i; } x; x.f = f;
  unsigned int u = x.i;
  u += 0x7fffu + ((u >> 16) & 1u);
  return (u16)(u >> 16);
}
__device__ __forceinline__ u16 f2bf_fast(float f) {     // round-half-up, 2 ops
  union { float f; unsigned int i; } x; x.f = f;
  return (u16)((x.i + 0x8000u) >> 16);
}

// Runtime dtype probe (R4-validated).
__device__ __forceinline__ int probe_is_f32(const void* p) {
  const unsigned int* w = (const unsigned int*)p;
  int cnt = 0;
#pragma unroll
  for (int i = 0; i < 64; ++i) {
    unsigned int lo = w[i] & 0xFFFFu;
    int e = (int)((lo >> 7) & 0xFFu);
    cnt += (e >= 117 && e <= 137) ? 1 : 0;
  }
  return cnt < 32;
}

__device__ __forceinline__ short8 ld8(const void* P, size_t off, int isf32) {
  if (isf32) {
    const float* q = (const float*)P + off;
    float4 x = *(const float4*)q;
    float4 y = *(const float4*)(q + 4);
    short8 r;
    r[0] = (short)f2bf(x.x); r[1] = (short)f2bf(x.y);
    r[2] = (short)f2bf(x.z); r[3] = (short)f2bf(x.w);
    r[4] = (short)f2bf(y.x); r[5] = (short)f2bf(y.y);
    r[6] = (short)f2bf(y.z); r[7] = (short)f2bf(y.w);
    return r;
  }
  return *(const short8*)((const u16*)P + off);
}

__device__ __forceinline__ float ldscalar(const void* P, size_t idx, int isf32) {
  return isf32 ? ((const float*)P)[idx] : bf2f(((const u16*)P)[idx]);
}

__device__ __forceinline__ short8 cvt8(float4 x, float4 y) {
  short8 r;
  r[0] = (short)f2bf_fast(x.x); r[1] = (short)f2bf_fast(x.y);
  r[2] = (short)f2bf_fast(x.z); r[3] = (short)f2bf_fast(x.w);
  r[4] = (short)f2bf_fast(y.x); r[5] = (short)f2bf_fast(y.y);
  r[6] = (short)f2bf_fast(y.z); r[7] = (short)f2bf_fast(y.w);
  return r;
}

// ---------------------------------------------------------------------------
// Pipelined GEMM core, templated on operand dtype (AF/BF: 1 = fp32 in memory).
// 128x128 C-tile of A[M,K] @ W[N,K]^T, BK=32, 4 waves 2x2, As/Bs = 4096 u16.
// Next-tile global loads are issued AFTER the LDS stores and stay in flight
// across both raw barriers (lgkmcnt-only, no vmcnt drain — R12-proven idiom).
// The vmcnt wait the compiler inserts lands at next iter's cvt/store, hidden
// behind barrier + MFMA.
// ---------------------------------------------------------------------------
template <int AF, int BF>
__device__ __forceinline__ void gemm_pipe(
    const void* __restrict__ A, const void* __restrict__ W,
    u16* As, u16* Bs, floatx4 acc[4][4], int m0, int n0, int K, int tid)
{
  const int lane = tid & 63, wv = tid >> 6;
  const int wm = wv >> 1, wn = wv & 1;
  const int g = lane >> 4, ml = lane & 15;
  const int r0 = tid >> 2, kc = (tid & 3) << 3;
  const size_t oA0 = (size_t)(m0 + r0) * K + kc;
  const size_t oA1 = (size_t)(m0 + r0 + 64) * K + kc;
  const size_t oB0 = (size_t)(n0 + r0) * K + kc;
  const size_t oB1 = (size_t)(n0 + r0 + 64) * K + kc;
  u16* Al0 = As + tid * 8;  u16* Al1 = As + (tid + 256) * 8;
  u16* Bl0 = Bs + tid * 8;  u16* Bl1 = Bs + (tid + 256) * 8;

  float4 fa0[2], fa1[2], fb0[2], fb1[2];
  short8 sa0, sa1, sb0, sb1;

#define LOADT(kt_) do {                                                        \
    if (AF) {                                                                  \
      const float* p0 = (const float*)A + oA0 + (kt_);                         \
      fa0[0] = ((const float4*)p0)[0]; fa0[1] = ((const float4*)p0)[1];        \
      const float* p1 = (const float*)A + oA1 + (kt_);                         \
      fa1[0] = ((const float4*)p1)[0]; fa1[1] = ((const float4*)p1)[1];        \
    } else {                                                                   \
      sa0 = *(const short8*)((const u16*)A + oA0 + (kt_));                     \
      sa1 = *(const short8*)((const u16*)A + oA1 + (kt_));                     \
    }                                                                          \
    if (BF) {                                                                  \
      const float* q0 = (const float*)W + oB0 + (kt_);                         \
      fb0[0] = ((const float4*)q0)[0]; fb0[1] = ((const float4*)q0)[1];        \
      const float* q1 = (const float*)W + oB1 + (kt_);                         \
      fb1[0] = ((const float4*)q1)[0]; fb1[1] = ((const float4*)q1)[1];        \
    } else {                                                                   \
      sb0 = *(const short8*)((const u16*)W + oB0 + (kt_));                     \
      sb1 = *(const short8*)((const u16*)W + oB1 + (kt_));                     \
    }                                                                          \
  } while (0)

  LOADT(0);
  for (int kt = 0; kt < K; kt += 32) {
    // (a) prev iter's frag reads (lgkm) done; global prefetch NOT drained
    __asm__ __volatile__("s_waitcnt lgkmcnt(0)\n\ts_barrier" ::: "memory");
    *(short8*)Al0 = AF ? cvt8(fa0[0], fa0[1]) : sa0;   // vmcnt wait lands here
    *(short8*)Al1 = AF ? cvt8(fa1[0], fa1[1]) : sa1;
    *(short8*)Bl0 = BF ? cvt8(fb0[0], fb0[1]) : sb0;
    *(short8*)Bl1 = BF ? cvt8(fb1[0], fb1[1]) : sb1;
    const int nk = (kt + 32 < K) ? kt + 32 : 0;        // dummy reload last iter
    LOADT(nk);                                          // in flight across (b)+MFMA
    // (b) ds_writes visible to all waves
    __asm__ __volatile__("s_waitcnt lgkmcnt(0)\n\ts_barrier" ::: "memory");
    short8 af[4], bf[4];
#pragma unroll
    for (int i = 0; i < 4; ++i)
      af[i] = *(const short8*)(As + (wm * 64 + i * 16 + ml) * 32 + g * 8);
#pragma unroll
    for (int j = 0; j < 4; ++j)
      bf[j] = *(const short8*)(Bs + (wn * 64 + j * 16 + ml) * 32 + g * 8);
#pragma unroll
    for (int i = 0; i < 4; ++i)
#pragma unroll
      for (int j = 0; j < 4; ++j)
        acc[i][j] = __builtin_amdgcn_mfma_f32_16x16x32_bf16(af[i], bf[j], acc[i][j], 0, 0, 0);
  }
#undef LOADT
  __asm__ __volatile__("s_waitcnt vmcnt(0)" ::: "memory");  // drain dummy
}

// ---------------------------------------------------------------------------
// QKV epilogue: z=0 (Q) scaled by QSCALE into [B,H,S,D]; z=1 (K) [B,H,S,D];
// z=2 (V) TRANSPOSED into [B,H,D,S] (4-wide packed along s).
// ---------------------------------------------------------------------------
__device__ __forceinline__ void qkv_epilogue(
    floatx4 acc[4][4], const void* Bi, int cF32, u16* O, int m0, int n0,
    int tid, int z)
{
  const int lane = tid & 63, wv = tid >> 6;
  const int wm = wv >> 1, wn = wv & 1, g = lane >> 4, ml = lane & 15;
  const float sc = (z == 0) ? QSCALE : 1.0f;
#pragma unroll
  for (int j = 0; j < 4; ++j) {
    int gn = n0 + wn * 64 + j * 16 + ml;
    float bvv = ldscalar(Bi, (size_t)gn, cF32);
    int h = gn >> 6, d = gn & 63;
    if (z == 2) {
#pragma unroll
      for (int i = 0; i < 4; ++i) {
        int gm0 = m0 + wm * 64 + i * 16 + g * 4;
        int b = gm0 >> 11, s0 = gm0 & 2047;
        short4v pk;
#pragma unroll
        for (int r = 0; r < 4; ++r) pk[r] = (short)f2bf_fast(acc[i][j][r] + bvv);
        *(short4v*)(O + ((((size_t)b * 16 + h) * 64 + d) * 2048 + s0)) = pk;
      }
    } else {
#pragma unroll
      for (int i = 0; i < 4; ++i)
#pragma unroll
        for (int r = 0; r < 4; ++r) {
          int gm = m0 + wm * 64 + i * 16 + g * 4 + r;
          int b = gm >> 11, s = gm & 2047;
          O[(((size_t)b * 16 + h) * 2048 + s) * 64 + d] =
              f2bf_fast((acc[i][j][r] + bvv) * sc);
        }
    }
  }
}

// grid (32 m, 8 n, 3): linear ≡ m (mod 8) -> XCD-local A rows, W reused in L2.
__global__ __launch_bounds__(256) void qkv_gemm(
    const void* __restrict__ Xq, const void* __restrict__ Xk, const void* __restrict__ Xv,
    const void* __restrict__ Wq, const void* __restrict__ Wk, const void* __restrict__ Wv,
    const void* __restrict__ Bq, const void* __restrict__ Bk, const void* __restrict__ Bv,
    u16* __restrict__ Oq, u16* __restrict__ Ok, u16* __restrict__ Ov)
{
  __align__(16) __shared__ u16 As[4096];
  __align__(16) __shared__ u16 Bs[4096];
  const int z = blockIdx.z;
  const void* X  = (z == 0) ? Xq : (z == 1) ? Xk : Xv;
  const void* W  = (z == 0) ? Wq : (z == 1) ? Wk : Wv;
  const void* Bi = (z == 0) ? Bq : (z == 1) ? Bk : Bv;
  u16* O = (z == 0) ? Oq : (z == 1) ? Ok : Ov;
  const int aF32 = probe_is_f32(X);
  const int bF32 = probe_is_f32(W);
  const int cF32 = probe_is_f32(Bi);
  const int tid = threadIdx.x;
  const int m0 = blockIdx.x * 128, n0 = blockIdx.y * 128;
  floatx4 acc[4][4] = {};
  if (aF32 && bF32)       gemm_pipe<1, 1>(X, W, As, Bs, acc, m0, n0, 1024, tid);
  else if (!aF32 && !bF32) gemm_pipe<0, 0>(X, W, As, Bs, acc, m0, n0, 1024, tid);
  else if (aF32)          gemm_pipe<1, 0>(X, W, As, Bs, acc, m0, n0, 1024, tid);
  else                    gemm_pipe<0, 1>(X, W, As, Bs, acc, m0, n0, 1024, tid);
  qkv_epilogue(acc, Bi, cF32, O, m0, n0, tid, z);
}

// ---------------------------------------------------------------------------
// Output projection: attn[B,S,E](bf16 ws) @ Wo^T + bo -> fp32 d_out.
// grid (32 m, 8 n) XCD-swizzled.
// ---------------------------------------------------------------------------
__global__ __launch_bounds__(256) void out_gemm(
    const u16* __restrict__ X, const void* __restrict__ W,
    const void* __restrict__ Bi, float* __restrict__ O)
{
  __align__(16) __shared__ u16 As[4096];
  __align__(16) __shared__ u16 Bs[4096];
  const int bF32 = probe_is_f32(W);
  const int cF32 = probe_is_f32(Bi);
  const int tid = threadIdx.x;
  const int m0 = blockIdx.x * 128, n0 = blockIdx.y * 128;
  floatx4 acc[4][4] = {};
  if (bF32) gemm_pipe<0, 1>(X, W, As, Bs, acc, m0, n0, 1024, tid);
  else      gemm_pipe<0, 0>(X, W, As, Bs, acc, m0, n0, 1024, tid);
  const int lane = tid & 63, wv = tid >> 6;
  const int wm = wv >> 1, wn = wv & 1, g = lane >> 4, ml = lane & 15;
#pragma unroll
  for (int j = 0; j < 4; ++j) {
    int gn = n0 + wn * 64 + j * 16 + ml;
    float bvv = ldscalar(Bi, (size_t)gn, cF32);
#pragma unroll
    for (int i = 0; i < 4; ++i)
#pragma unroll
      for (int r = 0; r < 4; ++r) {
        int gm = m0 + wm * 64 + i * 16 + g * 4 + r;
        O[(size_t)gm * 1024 + gn] = acc[i][j][r] + bvv;
      }
  }
}

// ---------------------------------------------------------------------------
// Flash attention v6 (R13, unchanged): dbuf Ks/Vt with vmcnt(4) barriers,
// 2 q-tiles/block, grid (16,32). Last-iter prefetch overruns into adjacent
// workspace tensors (allocated; values unused).
// ---------------------------------------------------------------------------
__global__ __launch_bounds__(256) void flash_attn(
    const u16* __restrict__ Q, const u16* __restrict__ K, const u16* __restrict__ V,
    const int* __restrict__ Mask, u16* __restrict__ O)
{
  __align__(16) __shared__ u16 Ks[2][4096];
  __align__(16) __shared__ u16 Vt[2][4096];
  __align__(16) __shared__ u16 Ps[4][16 * 72];
  __align__(16) __shared__ int Ms[64];
  __shared__ int Wok[4];

  const int qt2 = blockIdx.x;
  const int bh = blockIdx.y;
  const int b = bh >> 4, h = bh & 15;
  const int tid = threadIdx.x;
  const int lane = tid & 63, wv = tid >> 6;
  const int g = lane >> 4, ml = lane & 15;

  const size_t baseQ  = (((size_t)b * 16 + h) * 2048 + (size_t)qt2 * 128) * 64;
  const size_t baseKV = ((size_t)b * 16 + h) * 2048 * 64;  // V is [B,H,D,S]

  {
    int la = 1;
#pragma unroll
    for (int i = 0; i < 8; ++i) la &= Mask[b * 2048 + tid * 8 + i];
    int wall = __all(la != 0);
    if (lane == 0) Wok[wv] = wall;
  }

  short8 qf[2][2];
#pragma unroll
  for (int u = 0; u < 2; ++u)
#pragma unroll
    for (int ks = 0; ks < 2; ++ks)
      qf[u][ks] = *(const short8*)(Q + baseQ +
          (size_t)(u * 64 + wv * 16 + ml) * 64 + ks * 32 + g * 8);

  const u16* kg[2]; const u16* vg[2];
#pragma unroll
  for (int t = 0; t < 2; ++t) {
    int s = tid + t * 256;
    int krow = s >> 3, kch = (s & 7) ^ (krow & 7);
    kg[t] = K + baseKV + (size_t)krow * 64 + kch * 8;
    int vd = s >> 3,  vch = (s & 7) ^ (vd & 7);
    vg[t] = V + baseKV + (size_t)vd * 2048 + vch * 8;
  }

  __syncthreads();
  const bool maskall = Wok[0] && Wok[1] && Wok[2] && Wok[3];

#define STAGE_FA(buf_) do {                                                    \
    u16* kb_ = Ks[buf_] + (size_t)(tid & 448) * 8;                             \
    u16* vb_ = Vt[buf_] + (size_t)(tid & 448) * 8;                             \
    __builtin_amdgcn_global_load_lds((const AS_GLOBAL unsigned int*)kg[0],     \
                                     (AS_LDS unsigned int*)kb_, 16, 0, 0);     \
    __builtin_amdgcn_global_load_lds((const AS_GLOBAL unsigned int*)kg[1],     \
                                     (AS_LDS unsigned int*)(kb_ + 2048), 16, 0, 0); \
    __builtin_amdgcn_global_load_lds((const AS_GLOBAL unsigned int*)vg[0],     \
                                     (AS_LDS unsigned int*)vb_, 16, 0, 0);     \
    __builtin_amdgcn_global_load_lds((const AS_GLOBAL unsigned int*)vg[1],     \
                                     (AS_LDS unsigned int*)(vb_ + 2048), 16, 0, 0); \
    kg[0] += 4096; kg[1] += 4096; vg[0] += 64; vg[1] += 64;                    \
  } while (0)

  floatx4 oacc[2][4] = {};
  float lp[2][4] = {};

  STAGE_FA(0);
  int buf = 0;
  for (int kv0 = 0; kv0 < 2048; kv0 += 64) {
    STAGE_FA(buf ^ 1);
    __asm__ __volatile__("s_waitcnt vmcnt(4)\n\ts_barrier" ::: "memory");
    if (!maskall && tid < 64) Ms[tid] = Mask[b * 2048 + kv0 + tid];
    const u16* Kc = Ks[buf];
    const u16* Vc = Vt[buf];

#pragma unroll
    for (int u = 0; u < 2; ++u) {
      float sv[4][4];
#pragma unroll
      for (int j = 0; j < 4; ++j) {
        floatx4 a = {0.f, 0.f, 0.f, 0.f};
        int row = j * 16 + ml;
#pragma unroll
        for (int ks = 0; ks < 2; ++ks) {
          short8 kb = *(const short8*)(Kc + row * 64 + ((((ks << 2) + g) ^ (row & 7)) << 3));
          a = __builtin_amdgcn_mfma_f32_16x16x32_bf16(qf[u][ks], kb, a, 0, 0, 0);
        }
#pragma unroll
        for (int r = 0; r < 4; ++r) sv[j][r] = a[r];
      }
      if (!maskall) {
        int mok[4];
#pragma unroll
        for (int j = 0; j < 4; ++j) mok[j] = Ms[j * 16 + ml];
#pragma unroll
        for (int j = 0; j < 4; ++j)
#pragma unroll
          for (int r = 0; r < 4; ++r)
            sv[j][r] = (mok[j] == 0) ? -1.0e30f : sv[j][r];
      }
#pragma unroll
      for (int j = 0; j < 4; ++j)
#pragma unroll
        for (int r = 0; r < 4; ++r) {
          float p = __builtin_amdgcn_exp2f(sv[j][r]);
          sv[j][r] = p;
          lp[u][r] += p;
        }
#pragma unroll
      for (int j = 0; j < 4; ++j)
#pragma unroll
        for (int r = 0; r < 4; ++r)
          Ps[wv][(g * 4 + r) * 72 + j * 16 + ml] = f2bf_fast(sv[j][r]);

      __asm__ __volatile__("s_waitcnt lgkmcnt(0)" ::: "memory");

      short8 pa[2];
#pragma unroll
      for (int j2 = 0; j2 < 2; ++j2)
        pa[j2] = *(const short8*)(&Ps[wv][ml * 72 + j2 * 32 + g * 8]);
#pragma unroll
      for (int t = 0; t < 4; ++t)
#pragma unroll
        for (int j2 = 0; j2 < 2; ++j2) {
          short8 vb = *(const short8*)(Vc + (t * 16 + ml) * 64 + ((((j2 << 2) + g) ^ (ml & 7)) << 3));
          oacc[u][t] = __builtin_amdgcn_mfma_f32_16x16x32_bf16(pa[j2], vb, oacc[u][t], 0, 0, 0);
        }
    }
    __asm__ __volatile__("s_waitcnt lgkmcnt(0)\n\ts_barrier" ::: "memory");
    buf ^= 1;
  }
#undef STAGE_FA
  __asm__ __volatile__("s_waitcnt vmcnt(0)" ::: "memory");

#pragma unroll
  for (int u = 0; u < 2; ++u) {
    float inv[4];
#pragma unroll
    for (int r = 0; r < 4; ++r) {
      float l = lp[u][r];
      l += __shfl_xor(l, 1);
      l += __shfl_xor(l, 2);
      l += __shfl_xor(l, 4);
      l += __shfl_xor(l, 8);
      inv[r] = (l > 0.f) ? 1.0f / l : 0.f;
    }
#pragma unroll
    for (int t = 0; t < 4; ++t)
#pragma unroll
      for (int r = 0; r < 4; ++r) {
        int q = qt2 * 128 + u * 64 + wv * 16 + g * 4 + r;
        int d = t * 16 + ml;
        O[((size_t)b * 2048 + q) * 1024 + h * 64 + d] = f2bf_fast(oacc[u][t][r] * inv[r]);
      }
  }
}

// ---------------------------------------------------------------------------
extern "C" void kernel_launch(void* const* d_in, const int* in_sizes, int n_in,
                              void* d_out, int out_size, void* d_ws, size_t ws_size,
                              hipStream_t stream) {
  const void* q_in = d_in[0];
  const void* k_in = d_in[1];
  const void* v_in = d_in[2];
  const int* mask = (const int*)d_in[3];
  const void* Wq = d_in[4];  const void* bq = d_in[5];
  const void* Wk = d_in[6];  const void* bk = d_in[7];
  const void* Wv = d_in[8];  const void* bv = d_in[9];
  const void* Wo = d_in[10]; const void* bo = d_in[11];

  const size_t NTOK = (size_t)2 * 2048 * 1024;   // 4,194,304
  u16* Qp = (u16*)d_ws;       // [B,H,S,D] bf16, pre-scaled
  u16* Kp = Qp + NTOK;        // [B,H,S,D] bf16
  u16* Vp = Kp + NTOK;        // [B,H,D,S] bf16 (transposed)
  u16* Ao = Vp + NTOK;        // [B,S,E]  bf16

  qkv_gemm<<<dim3(32, 8, 3), 256, 0, stream>>>(q_in, k_in, v_in,
                                               Wq, Wk, Wv, bq, bk, bv,
                                               Qp, Kp, Vp);
  flash_attn<<<dim3(16, 32), 256, 0, stream>>>(Qp, Kp, Vp, mask, Ao);
  out_gemm<<<dim3(32, 8), 256, 0, stream>>>(Ao, Wo, bo, (float*)d_out);
}

// Round 15
// 258.141 us; speedup vs baseline: 1.0667x; 1.0667x over previous
//
#include <hip/hip_runtime.h>
#include <stdint.h>

typedef unsigned short u16;
typedef __attribute__((ext_vector_type(8))) short short8;
typedef __attribute__((ext_vector_type(4))) short short4v;
typedef __attribute__((ext_vector_type(4))) float floatx4;

#define AS_GLOBAL __attribute__((address_space(1)))
#define AS_LDS    __attribute__((address_space(3)))

// exp2 argument scale folded into Qp: 1/sqrt(1024) * log2(e)
#define QSCALE 0.045084220f

__device__ __forceinline__ float bf2f(u16 u) {
  union { unsigned int i; float f; } x; x.i = ((unsigned int)u) << 16; return x.f;
}
__device__ __forceinline__ u16 f2bf(float f) {          // RNE
  union { float f; unsigned int i; } x; x.f = f;
  unsigned int u = x.i;
  u += 0x7fffu + ((u >> 16) & 1u);
  return (u16)(u >> 16);
}
__device__ __forceinline__ u16 f2bf_fast(float f) {     // round-half-up, 2 ops
  union { float f; unsigned int i; } x; x.f = f;
  return (u16)((x.i + 0x8000u) >> 16);
}

// Runtime dtype probe (R4-validated).
__device__ __forceinline__ int probe_is_f32(const void* p) {
  const unsigned int* w = (const unsigned int*)p;
  int cnt = 0;
#pragma unroll
  for (int i = 0; i < 64; ++i) {
    unsigned int lo = w[i] & 0xFFFFu;
    int e = (int)((lo >> 7) & 0xFFu);
    cnt += (e >= 117 && e <= 137) ? 1 : 0;
  }
  return cnt < 32;
}

__device__ __forceinline__ short8 ld8(const void* P, size_t off, int isf32) {
  if (isf32) {
    const float* q = (const float*)P + off;
    float4 x = *(const float4*)q;
    float4 y = *(const float4*)(q + 4);
    short8 r;
    r[0] = (short)f2bf(x.x); r[1] = (short)f2bf(x.y);
    r[2] = (short)f2bf(x.z); r[3] = (short)f2bf(x.w);
    r[4] = (short)f2bf(y.x); r[5] = (short)f2bf(y.y);
    r[6] = (short)f2bf(y.z); r[7] = (short)f2bf(y.w);
    return r;
  }
  return *(const short8*)((const u16*)P + off);
}

__device__ __forceinline__ float ldscalar(const void* P, size_t idx, int isf32) {
  return isf32 ? ((const float*)P)[idx] : bf2f(((const u16*)P)[idx]);
}

// ---------------------------------------------------------------------------
// cvt7: one-shot fp32->bf16 of 3 X tensors + 4 W tensors. grid (1024, 7).
// ---------------------------------------------------------------------------
__global__ __launch_bounds__(256) void cvt7(
    const void* s0, const void* s1, const void* s2, const void* s3,
    const void* s4, const void* s5, const void* s6,
    u16* d0, u16* d1, u16* d2, u16* d3, u16* d4, u16* d5, u16* d6)
{
  const int z = blockIdx.y;
  const void* src; u16* dst; int n;
  switch (z) {
    case 0: src = s0; dst = d0; n = 4194304; break;
    case 1: src = s1; dst = d1; n = 4194304; break;
    case 2: src = s2; dst = d2; n = 4194304; break;
    case 3: src = s3; dst = d3; n = 1048576; break;
    case 4: src = s4; dst = d4; n = 1048576; break;
    case 5: src = s5; dst = d5; n = 1048576; break;
    default: src = s6; dst = d6; n = 1048576; break;
  }
  const int isf32 = probe_is_f32(src);
  for (int i = blockIdx.x * 256 + threadIdx.x; i * 4 < n; i += gridDim.x * 256) {
    if (isf32) {
      float4 x = ((const float4*)src)[i];
      short4v r;
      r[0] = (short)f2bf(x.x); r[1] = (short)f2bf(x.y);
      r[2] = (short)f2bf(x.z); r[3] = (short)f2bf(x.w);
      *(short4v*)(dst + (size_t)i * 4) = r;
    } else {
      *(short4v*)(dst + (size_t)i * 4) = ((const short4v*)src)[i];
    }
  }
}

// ---------------------------------------------------------------------------
// bf16 MFMA GEMM core v3 (R12-proven best): BK=32 + double-buffered LDS with
// raw barriers; prefetch stays in flight across the barrier (vmcnt(4) never 0
// inside the loop) — the AITER/hipBLASLt pattern. As/Bs each 8192 u16.
// ---------------------------------------------------------------------------
__device__ __forceinline__ void gemm_core_bf16(
    const u16* __restrict__ A, const u16* __restrict__ W,
    u16* As, u16* Bs, floatx4 acc[4][4], int m0, int n0, int K, int tid)
{
  const int lane = tid & 63, wv = tid >> 6;
  const int wm = wv >> 1, wn = wv & 1;
  const int g = lane >> 4, ml = lane & 15;
  const int r0 = tid >> 2, kc = (tid & 3) << 3;
  const u16* Ag0 = A + (size_t)(m0 + r0) * K + kc;
  const u16* Ag1 = A + (size_t)(m0 + r0 + 64) * K + kc;
  const u16* Bg0 = W + (size_t)(n0 + r0) * K + kc;
  const u16* Bg1 = W + (size_t)(n0 + r0 + 64) * K + kc;

#define STAGE_QKV(buf_, kt_) do {                                              \
    u16* a0 = As + (buf_) * 4096 + tid * 8;                                    \
    u16* b0 = Bs + (buf_) * 4096 + tid * 8;                                    \
    __builtin_amdgcn_global_load_lds((const AS_GLOBAL unsigned int*)(Ag0 + (kt_)), \
                                     (AS_LDS unsigned int*)a0, 16, 0, 0);      \
    __builtin_amdgcn_global_load_lds((const AS_GLOBAL unsigned int*)(Ag1 + (kt_)), \
                                     (AS_LDS unsigned int*)(a0 + 2048), 16, 0, 0); \
    __builtin_amdgcn_global_load_lds((const AS_GLOBAL unsigned int*)(Bg0 + (kt_)), \
                                     (AS_LDS unsigned int*)b0, 16, 0, 0);      \
    __builtin_amdgcn_global_load_lds((const AS_GLOBAL unsigned int*)(Bg1 + (kt_)), \
                                     (AS_LDS unsigned int*)(b0 + 2048), 16, 0, 0); \
  } while (0)

  STAGE_QKV(0, 0);
  int buf = 0;
#pragma unroll 2
  for (int kt = 0; kt < K; kt += 32) {
    const int nk = (kt + 32 < K) ? (kt + 32) : 0;   // dummy reload on last iter
    STAGE_QKV(buf ^ 1, nk);
    __asm__ __volatile__("s_waitcnt vmcnt(4)\n\ts_barrier" ::: "memory");
    const u16* Ac = As + buf * 4096;
    const u16* Bc = Bs + buf * 4096;
    short8 af[4], bf[4];
#pragma unroll
    for (int i = 0; i < 4; ++i)
      af[i] = *(const short8*)(Ac + (wm * 64 + i * 16 + ml) * 32 + g * 8);
#pragma unroll
    for (int j = 0; j < 4; ++j)
      bf[j] = *(const short8*)(Bc + (wn * 64 + j * 16 + ml) * 32 + g * 8);
#pragma unroll
    for (int i = 0; i < 4; ++i)
#pragma unroll
      for (int j = 0; j < 4; ++j)
        acc[i][j] = __builtin_amdgcn_mfma_f32_16x16x32_bf16(af[i], bf[j], acc[i][j], 0, 0, 0);
    __asm__ __volatile__("s_waitcnt lgkmcnt(0)\n\ts_barrier" ::: "memory");
    buf ^= 1;
  }
#undef STAGE_QKV
  __asm__ __volatile__("s_waitcnt vmcnt(0)" ::: "memory");
}

// R7-proven fallback core: BK=32, cvt-in-staging. (As/Bs = 4096 u16)
__device__ __forceinline__ void gemm_core_cvt(
    const void* __restrict__ A, const void* __restrict__ W, int aF32, int bF32,
    u16* As, u16* Bs, floatx4 acc[4][4], int m0, int n0, int K, int tid)
{
  const int lane = tid & 63, wv = tid >> 6;
  const int wm = wv >> 1, wn = wv & 1;
  const int g = lane >> 4, ml = lane & 15;
  const int r0 = tid >> 2, kc = (tid & 3) << 3;
  const size_t offA0 = (size_t)(m0 + r0) * K + kc;
  const size_t offA1 = (size_t)(m0 + r0 + 64) * K + kc;
  const size_t offB0 = (size_t)(n0 + r0) * K + kc;
  const size_t offB1 = (size_t)(n0 + r0 + 64) * K + kc;
  u16* Al0 = As + tid * 8;  u16* Al1 = As + (tid + 256) * 8;
  u16* Bl0 = Bs + tid * 8;  u16* Bl1 = Bs + (tid + 256) * 8;
  for (int kt = 0; kt < K; kt += 32) {
    short8 a0 = ld8(A, offA0 + kt, aF32);
    short8 a1 = ld8(A, offA1 + kt, aF32);
    short8 b0 = ld8(W, offB0 + kt, bF32);
    short8 b1 = ld8(W, offB1 + kt, bF32);
    *(short8*)Al0 = a0;  *(short8*)Al1 = a1;
    *(short8*)Bl0 = b0;  *(short8*)Bl1 = b1;
    __syncthreads();
    short8 af[4], bf[4];
#pragma unroll
    for (int i = 0; i < 4; ++i)
      af[i] = *(const short8*)(As + (wm * 64 + i * 16 + ml) * 32 + g * 8);
#pragma unroll
    for (int j = 0; j < 4; ++j)
      bf[j] = *(const short8*)(Bs + (wn * 64 + j * 16 + ml) * 32 + g * 8);
#pragma unroll
    for (int i = 0; i < 4; ++i)
#pragma unroll
      for (int j = 0; j < 4; ++j)
        acc[i][j] = __builtin_amdgcn_mfma_f32_16x16x32_bf16(af[i], bf[j], acc[i][j], 0, 0, 0);
    __syncthreads();
  }
}

// ---------------------------------------------------------------------------
// QKV epilogue: z=0 (Q) scaled by QSCALE into [B,H,S,D]; z=1 (K) [B,H,S,D];
// z=2 (V) TRANSPOSED into [B,H,D,S] (4-wide packed along s).
// ---------------------------------------------------------------------------
__device__ __forceinline__ void qkv_epilogue(
    floatx4 acc[4][4], const void* Bi, int cF32, u16* O, int m0, int n0,
    int tid, int z)
{
  const int lane = tid & 63, wv = tid >> 6;
  const int wm = wv >> 1, wn = wv & 1, g = lane >> 4, ml = lane & 15;
  const float sc = (z == 0) ? QSCALE : 1.0f;
#pragma unroll
  for (int j = 0; j < 4; ++j) {
    int gn = n0 + wn * 64 + j * 16 + ml;
    float bvv = ldscalar(Bi, (size_t)gn, cF32);
    int h = gn >> 6, d = gn & 63;
    if (z == 2) {
#pragma unroll
      for (int i = 0; i < 4; ++i) {
        int gm0 = m0 + wm * 64 + i * 16 + g * 4;
        int b = gm0 >> 11, s0 = gm0 & 2047;
        short4v pk;
#pragma unroll
        for (int r = 0; r < 4; ++r) pk[r] = (short)f2bf_fast(acc[i][j][r] + bvv);
        *(short4v*)(O + ((((size_t)b * 16 + h) * 64 + d) * 2048 + s0)) = pk;
      }
    } else {
#pragma unroll
      for (int i = 0; i < 4; ++i)
#pragma unroll
        for (int r = 0; r < 4; ++r) {
          int gm = m0 + wm * 64 + i * 16 + g * 4 + r;
          int b = gm >> 11, s = gm & 2047;
          O[(((size_t)b * 16 + h) * 2048 + s) * 64 + d] =
              f2bf_fast((acc[i][j][r] + bvv) * sc);
        }
    }
  }
}

// grid (32 m, 8 n, 3): linear ≡ m (mod 8) -> XCD-local A rows, W reused in L2.
__global__ __launch_bounds__(256) void qkv_gemm_bf16(
    const u16* __restrict__ Xq, const u16* __restrict__ Xk, const u16* __restrict__ Xv,
    const u16* __restrict__ Wq, const u16* __restrict__ Wk, const u16* __restrict__ Wv,
    const void* __restrict__ Bq, const void* __restrict__ Bk, const void* __restrict__ Bv,
    u16* __restrict__ Oq, u16* __restrict__ Ok, u16* __restrict__ Ov)
{
  __align__(16) __shared__ u16 As[8192];
  __align__(16) __shared__ u16 Bs[8192];
  const int z = blockIdx.z;
  const u16* X = (z == 0) ? Xq : (z == 1) ? Xk : Xv;
  const u16* W = (z == 0) ? Wq : (z == 1) ? Wk : Wv;
  const void* Bi = (z == 0) ? Bq : (z == 1) ? Bk : Bv;
  u16* O = (z == 0) ? Oq : (z == 1) ? Ok : Ov;
  const int tid = threadIdx.x;
  const int m0 = blockIdx.x * 128, n0 = blockIdx.y * 128;
  floatx4 acc[4][4] = {};
  gemm_core_bf16(X, W, As, Bs, acc, m0, n0, 1024, tid);
  const int cF32 = probe_is_f32(Bi);
  qkv_epilogue(acc, Bi, cF32, O, m0, n0, tid, z);
}

__global__ __launch_bounds__(256) void qkv_gemm_cvt(
    const void* __restrict__ Xq, const void* __restrict__ Xk, const void* __restrict__ Xv,
    const void* __restrict__ Wq, const void* __restrict__ Wk, const void* __restrict__ Wv,
    const void* __restrict__ Bq, const void* __restrict__ Bk, const void* __restrict__ Bv,
    u16* __restrict__ Oq, u16* __restrict__ Ok, u16* __restrict__ Ov)
{
  __align__(16) __shared__ u16 As[4096];
  __align__(16) __shared__ u16 Bs[4096];
  const int z = blockIdx.z;
  const void* X  = (z == 0) ? Xq : (z == 1) ? Xk : Xv;
  const void* W  = (z == 0) ? Wq : (z == 1) ? Wk : Wv;
  const void* Bi = (z == 0) ? Bq : (z == 1) ? Bk : Bv;
  u16* O = (z == 0) ? Oq : (z == 1) ? Ok : Ov;
  const int aF32 = probe_is_f32(X);
  const int bF32 = probe_is_f32(W);
  const int cF32 = probe_is_f32(Bi);
  const int tid = threadIdx.x;
  const int m0 = blockIdx.y * 128, n0 = blockIdx.x * 128;
  floatx4 acc[4][4] = {};
  gemm_core_cvt(X, W, aF32, bF32, As, Bs, acc, m0, n0, 1024, tid);
  qkv_epilogue(acc, Bi, cF32, O, m0, n0, tid, z);
}

// ---------------------------------------------------------------------------
// Output projection: 128x128 tiles, grid (32 m, 8 n), dbuf core, fp32 store.
// ---------------------------------------------------------------------------
__global__ __launch_bounds__(256) void out_gemm_bf16(
    const u16* __restrict__ X, const u16* __restrict__ W,
    const void* __restrict__ Bi, float* __restrict__ O)
{
  __align__(16) __shared__ u16 As[8192];
  __align__(16) __shared__ u16 Bs[8192];
  const int tid = threadIdx.x;
  const int m0 = blockIdx.x * 128, n0 = blockIdx.y * 128;
  floatx4 acc[4][4] = {};
  gemm_core_bf16(X, W, As, Bs, acc, m0, n0, 1024, tid);
  const int cF32 = probe_is_f32(Bi);
  const int lane = tid & 63, wv = tid >> 6;
  const int wm = wv >> 1, wn = wv & 1, g = lane >> 4, ml = lane & 15;
#pragma unroll
  for (int j = 0; j < 4; ++j) {
    int gn = n0 + wn * 64 + j * 16 + ml;
    float bvv = ldscalar(Bi, (size_t)gn, cF32);
#pragma unroll
    for (int i = 0; i < 4; ++i)
#pragma unroll
      for (int r = 0; r < 4; ++r) {
        int gm = m0 + wm * 64 + i * 16 + g * 4 + r;
        O[(size_t)gm * 1024 + gn] = acc[i][j][r] + bvv;
      }
  }
}

__global__ __launch_bounds__(256) void out_gemm_cvt(
    const u16* __restrict__ X, const void* __restrict__ W,
    const void* __restrict__ Bi, float* __restrict__ O)
{
  __align__(16) __shared__ u16 As[4096];
  __align__(16) __shared__ u16 Bs[4096];
  const int bF32 = probe_is_f32(W);
  const int cF32 = probe_is_f32(Bi);
  const int tid = threadIdx.x;
  const int m0 = blockIdx.y * 128, n0 = blockIdx.x * 128;
  floatx4 acc[4][4] = {};
  gemm_core_cvt(X, W, /*aF32=*/0, bF32, As, Bs, acc, m0, n0, 1024, tid);
  const int lane = tid & 63, wv = tid >> 6;
  const int wm = wv >> 1, wn = wv & 1, g = lane >> 4, ml = lane & 15;
#pragma unroll
  for (int j = 0; j < 4; ++j) {
    int gn = n0 + wn * 64 + j * 16 + ml;
    float bvv = ldscalar(Bi, (size_t)gn, cF32);
#pragma unroll
    for (int i = 0; i < 4; ++i)
#pragma unroll
      for (int r = 0; r < 4; ++r) {
        int gm = m0 + wm * 64 + i * 16 + g * 4 + r;
        O[(size_t)gm * 1024 + gn] = acc[i][j][r] + bvv;
      }
  }
}

// ---------------------------------------------------------------------------
// Flash attention v5 (R12-proven): kv-tile 64, LDS 25.3 KB -> all 4 blocks/CU
// resident; async swizzled staging; no-max softmax; mask hoist.
// ---------------------------------------------------------------------------
__global__ __launch_bounds__(256) void flash_attn(
    const u16* __restrict__ Q, const u16* __restrict__ K, const u16* __restrict__ V,
    const int* __restrict__ Mask, u16* __restrict__ O)
{
  __align__(16) __shared__ u16 Ks[64 * 64];
  __align__(16) __shared__ u16 Vt[64 * 64];
  __align__(16) __shared__ u16 Ps[4][16 * 72];
  __align__(16) __shared__ int Ms[64];
  __shared__ int Wok[4];

  const int qt = blockIdx.x;
  const int bh = blockIdx.y;
  const int b = bh >> 4, h = bh & 15;
  const int tid = threadIdx.x;
  const int lane = tid & 63, wv = tid >> 6;
  const int g = lane >> 4, ml = lane & 15;

  const size_t baseQ  = (((size_t)b * 16 + h) * 2048 + (size_t)qt * 64) * 64;
  const size_t baseKV = ((size_t)b * 16 + h) * 2048 * 64;  // V is [B,H,D,S]

  {
    int la = 1;
#pragma unroll
    for (int i = 0; i < 8; ++i) la &= Mask[b * 2048 + tid * 8 + i];
    int wall = __all(la != 0);
    if (lane == 0) Wok[wv] = wall;
  }

  short8 qf[2];
#pragma unroll
  for (int ks = 0; ks < 2; ++ks)
    qf[ks] = *(const short8*)(Q + baseQ + (size_t)(wv * 16 + ml) * 64 + ks * 32 + g * 8);

  const u16* kg[2]; const u16* vg[2];
  u16* kl[2]; u16* vl[2];
#pragma unroll
  for (int t = 0; t < 2; ++t) {
    int s = tid + t * 256;
    int krow = s >> 3, kch = (s & 7) ^ (krow & 7);
    kg[t] = K + baseKV + (size_t)krow * 64 + kch * 8;
    int vd = s >> 3,  vch = (s & 7) ^ (vd & 7);
    vg[t] = V + baseKV + (size_t)vd * 2048 + vch * 8;
    kl[t] = Ks + (size_t)((tid & 448) + t * 256) * 8;
    vl[t] = Vt + (size_t)((tid & 448) + t * 256) * 8;
  }

  __syncthreads();
  const bool maskall = Wok[0] && Wok[1] && Wok[2] && Wok[3];

  floatx4 oacc[4] = {};
  float lp[4] = {0.f, 0.f, 0.f, 0.f};

  for (int kv0 = 0; kv0 < 2048; kv0 += 64) {
    __syncthreads();
#pragma unroll
    for (int t = 0; t < 2; ++t) {
      __builtin_amdgcn_global_load_lds((const AS_GLOBAL unsigned int*)kg[t],
                                       (AS_LDS unsigned int*)kl[t], 16, 0, 0);
      __builtin_amdgcn_global_load_lds((const AS_GLOBAL unsigned int*)vg[t],
                                       (AS_LDS unsigned int*)vl[t], 16, 0, 0);
      kg[t] += 64 * 64;
      vg[t] += 64;
    }
    if (!maskall && tid < 64) Ms[tid] = Mask[b * 2048 + kv0 + tid];
    __syncthreads();

    float sv[4][4];
#pragma unroll
    for (int j = 0; j < 4; ++j) {
      floatx4 a = {0.f, 0.f, 0.f, 0.f};
      int row = j * 16 + ml;
#pragma unroll
      for (int ks = 0; ks < 2; ++ks) {
        short8 kb = *(const short8*)(Ks + row * 64 + ((((ks << 2) + g) ^ (row & 7)) << 3));
        a = __builtin_amdgcn_mfma_f32_16x16x32_bf16(qf[ks], kb, a, 0, 0, 0);
      }
#pragma unroll
      for (int r = 0; r < 4; ++r) sv[j][r] = a[r];
    }
    if (!maskall) {
      int mok[4];
#pragma unroll
      for (int j = 0; j < 4; ++j) mok[j] = Ms[j * 16 + ml];
#pragma unroll
      for (int j = 0; j < 4; ++j)
#pragma unroll
        for (int r = 0; r < 4; ++r)
          sv[j][r] = (mok[j] == 0) ? -1.0e30f : sv[j][r];
    }

#pragma unroll
    for (int j = 0; j < 4; ++j)
#pragma unroll
      for (int r = 0; r < 4; ++r) {
        float p = __builtin_amdgcn_exp2f(sv[j][r]);
        sv[j][r] = p;
        lp[r] += p;
      }

#pragma unroll
    for (int j = 0; j < 4; ++j)
#pragma unroll
      for (int r = 0; r < 4; ++r)
        Ps[wv][(g * 4 + r) * 72 + j * 16 + ml] = f2bf_fast(sv[j][r]);

    __asm__ __volatile__("s_waitcnt lgkmcnt(0)" ::: "memory");

    short8 pa[2];
#pragma unroll
    for (int j2 = 0; j2 < 2; ++j2)
      pa[j2] = *(const short8*)(&Ps[wv][ml * 72 + j2 * 32 + g * 8]);
#pragma unroll
    for (int t = 0; t < 4; ++t)
#pragma unroll
      for (int j2 = 0; j2 < 2; ++j2) {
        short8 vb = *(const short8*)(Vt + (t * 16 + ml) * 64 + ((((j2 << 2) + g) ^ (ml & 7)) << 3));
        oacc[t] = __builtin_amdgcn_mfma_f32_16x16x32_bf16(pa[j2], vb, oacc[t], 0, 0, 0);
      }
  }

  float inv[4];
#pragma unroll
  for (int r = 0; r < 4; ++r) {
    float l = lp[r];
    l += __shfl_xor(l, 1);
    l += __shfl_xor(l, 2);
    l += __shfl_xor(l, 4);
    l += __shfl_xor(l, 8);
    inv[r] = (l > 0.f) ? 1.0f / l : 0.f;
  }
#pragma unroll
  for (int t = 0; t < 4; ++t)
#pragma unroll
    for (int r = 0; r < 4; ++r) {
      int q = qt * 64 + wv * 16 + g * 4 + r;
      int d = t * 16 + ml;
      O[((size_t)b * 2048 + q) * 1024 + h * 64 + d] = f2bf_fast(oacc[t][r] * inv[r]);
    }
}

// ---------------------------------------------------------------------------
extern "C" void kernel_launch(void* const* d_in, const int* in_sizes, int n_in,
                              void* d_out, int out_size, void* d_ws, size_t ws_size,
                              hipStream_t stream) {
  const void* q_in = d_in[0];
  const void* k_in = d_in[1];
  const void* v_in = d_in[2];
  const int* mask = (const int*)d_in[3];
  const void* Wq = d_in[4];  const void* bq = d_in[5];
  const void* Wk = d_in[6];  const void* bk = d_in[7];
  const void* Wv = d_in[8];  const void* bv = d_in[9];
  const void* Wo = d_in[10]; const void* bo = d_in[11];

  const size_t NTOK = (size_t)2 * 2048 * 1024;   // 4,194,304
  const size_t NW   = (size_t)1024 * 1024;       // 1,048,576

  if (ws_size >= (size_t)67108864) {
    u16* CXq = (u16*)d_ws;
    u16* CXk = CXq + NTOK;
    u16* CXv = CXk + NTOK;
    u16* CWq = CXv + NTOK;
    u16* CWk = CWq + NW;
    u16* CWv = CWk + NW;
    u16* CWo = CWv + NW;
    u16* Qp  = CWo + NW;
    u16* Kp  = Qp + NTOK;
    u16* Vp  = Kp + NTOK;   // [B,H,D,S]
    u16* Ao  = Vp + NTOK;

    cvt7<<<dim3(1024, 7), 256, 0, stream>>>(q_in, k_in, v_in, Wq, Wk, Wv, Wo,
                                            CXq, CXk, CXv, CWq, CWk, CWv, CWo);
    qkv_gemm_bf16<<<dim3(32, 8, 3), 256, 0, stream>>>(CXq, CXk, CXv,
                                                      CWq, CWk, CWv,
                                                      bq, bk, bv, Qp, Kp, Vp);
    flash_attn<<<dim3(32, 32), 256, 0, stream>>>(Qp, Kp, Vp, mask, Ao);
    out_gemm_bf16<<<dim3(32, 8), 256, 0, stream>>>(Ao, CWo, bo, (float*)d_out);
  } else {
    u16* Qp = (u16*)d_ws;
    u16* Kp = Qp + NTOK;
    u16* Vp = Kp + NTOK;    // [B,H,D,S]
    u16* Ao = Vp + NTOK;

    qkv_gemm_cvt<<<dim3(8, 32, 3), 256, 0, stream>>>(q_in, k_in, v_in,
                                                     Wq, Wk, Wv, bq, bk, bv,
                                                     Qp, Kp, Vp);
    flash_attn<<<dim3(32, 32), 256, 0, stream>>>(Qp, Kp, Vp, mask, Ao);
    out_gemm_cvt<<<dim3(8, 32), 256, 0, stream>>>(Ao, Wo, bo, (float*)d_out);
  }
}